// Round 17
// baseline (2515.662 us; speedup 1.0000x reference)
//
#include <hip/hip_runtime.h>
#include <hip/hip_fp16.h>

#define B_   64
#define NB   128
#define E_   1024
#define DH   300
#define G3   900
#define G6   1800
#define OUTD 1924
#define SLICES 4
#define MROW 160   // u64/row: u32 data words [0..149], tag u64s [152..159]
#define BROWS 1856 // padded B rows for fused layer GEMM
#define WROW 152   // u32 per weight row in PK2T (150 pairs + 2 zero pads)

typedef _Float16 h2raw __attribute__((ext_vector_type(2)));
typedef _Float16 f16x8 __attribute__((ext_vector_type(8)));
typedef float f32x4 __attribute__((ext_vector_type(4)));

__device__ __forceinline__ float dot2f(unsigned int m2, unsigned int w, float acc) {
    h2raw a, b;
    __builtin_memcpy(&a, &m2, 4);
    __builtin_memcpy(&b, &w, 4);
    return __builtin_amdgcn_fdot2(a, b, acc, false);
}

__device__ __forceinline__ unsigned int packh2(float x, float y) {
    __half2 h;
    h.x = __float2half_rn(x);
    h.y = __float2half_rn(y);
    unsigned int u;
    __builtin_memcpy(&u, &h, 4);
    return u;
}

__device__ __forceinline__ float sigmoidf_(float x) { return 1.f / (1.f + __expf(-x)); }
__device__ __forceinline__ float tanh_fast(float x) { return 1.f - 2.f / (__expf(2.f * x) + 1.f); }

// ================= merged pack kernel =================
// seg A: PK2T [2][1800][152]  row-contiguous recurrent-weight rows (pads zero)
// seg B: APK1 [8192][512]     features f16 pairs
// seg C: BPKF [320][512]      fc1_w^T pairs
// seg D: BPKL [2][1856][160]  fused layer-B
// seg F: copy_feat            features -> out tail
// seg G: APK2 pad cols 150..159 = 0
#define NA (2 * 1800 * WROW)
#define NB_SEG (8192 * 512)
#define NC (320 * 512)
#define ND (2 * BROWS * 160)
#define NF (B_ * NB * 256)
#define NG (8192 * 10)
#define NTOT (NA + NB_SEG + NC + ND + NF + NG)

__global__ __launch_bounds__(256)
void pack_all(const float* __restrict__ gc_whh, const float* __restrict__ gp_wih,
              const float* __restrict__ features, const float* __restrict__ fc1_w,
              const float* __restrict__ gc_wih, const float* __restrict__ gp_whh,
              unsigned int* __restrict__ PK2T, unsigned int* __restrict__ APK1,
              unsigned int* __restrict__ BPKF, unsigned int* __restrict__ BPKL,
              float* __restrict__ out, unsigned int* __restrict__ APK2)
{
    long id = (long)blockIdx.x * 256 + threadIdx.x;
    if (id >= NTOT) return;
    if (id < NA) {
        const int l   = (int)(id / (1800 * WROW));
        const int rem = (int)(id % (1800 * WROW));
        const int R   = rem / WROW;
        const int kp  = rem % WROW;
        unsigned int u = 0u;
        if (kp < 150) {
            const int mat = R / G3;
            const int o   = R % G3;
            const float* W = (mat ? gp_wih : gc_whh) + (long)l * G3 * DH;
            const float2 v = *(const float2*)(W + (long)o * DH + 2 * kp);
            u = packh2(v.x, v.y);
        }
        PK2T[id] = u;
        return;
    }
    id -= NA;
    if (id < NB_SEG) {
        const long r = id >> 9;
        const int kp = (int)(id & 511);
        const float2 v = *(const float2*)(features + r * E_ + 2 * kp);
        APK1[id] = packh2(v.x, v.y);
        return;
    }
    id -= NB_SEG;
    if (id < NC) {
        const int n = (int)(id >> 9);
        const int kp = (int)(id & 511);
        unsigned int u = 0u;
        if (n < DH) u = packh2(fc1_w[(2 * kp) * DH + n], fc1_w[(2 * kp + 1) * DH + n]);
        BPKF[id] = u;
        return;
    }
    id -= NC;
    if (id < ND) {
        const int l   = (int)(id / (BROWS * 160));
        const int rem = (int)(id % (BROWS * 160));
        const int n   = rem / 160;
        const int kp  = rem % 160;
        unsigned int u = 0u;
        if (n < G6 && kp < 150) {
            const float* W = (n < G3 ? gc_wih : gp_whh) + (long)l * G3 * DH;
            const int o = (n < G3) ? n : n - G3;
            const float2 v = *(const float2*)(W + (long)o * DH + 2 * kp);
            u = packh2(v.x, v.y);
        }
        BPKL[id] = u;
        return;
    }
    id -= ND;
    if (id < NF) {
        const long r = id >> 8;
        const int  c = (int)(id & 255);
        const float4 v = ((const float4*)(features + r * E_))[c];
        ((float4*)(out + r * OUTD + 3 * DH))[c] = v;
        return;
    }
    id -= NF;
    {
        const long r = id / 10;
        const int c = (int)(id % 10);
        APK2[r * 160 + 150 + c] = 0u;
    }
}

// ---------------- MFMA f16 GEMM: per-wave 32x64 C tile, fragments straight from L2 ----------------
__device__ __forceinline__ f16x8 ldfrag(const unsigned int* p) {
    const uint4 u = *(const uint4*)p;
    f16x8 r;
    __builtin_memcpy(&r, &u, 16);
    return r;
}

template<int RELU, int PACKOUT>
__global__ __launch_bounds__(256)
void gemm_mf(const unsigned int* __restrict__ APK, int ldap,
             const unsigned int* __restrict__ BPK, int ldbp,
             const float* __restrict__ bias1, const float* __restrict__ bias2, int bsplit,
             float* __restrict__ C, int ldc,
             unsigned int* __restrict__ CPK, int ldcp,
             int N, int KSTEPS)
{
    const int lane = threadIdx.x & 63;
    const int wv = threadIdx.x >> 6;
    const int m0 = blockIdx.y * 128 + wv * 32;
    const int n0 = blockIdx.x * 64;
    const int ln = lane & 15;
    const int lh = lane >> 4;

    const unsigned int* a0p = APK + (long)(m0 + ln) * ldap + lh * 4;
    const unsigned int* a1p = a0p + 16L * ldap;
    const unsigned int* b0p = BPK + (long)(n0 + ln) * ldbp + lh * 4;

    f32x4 acc[2][4];
    #pragma unroll
    for (int mi = 0; mi < 2; ++mi)
        #pragma unroll
        for (int bj = 0; bj < 4; ++bj)
            acc[mi][bj] = (f32x4){0.f, 0.f, 0.f, 0.f};

    for (int ks = 0; ks < KSTEPS; ++ks) {
        const int off = ks * 16;
        const f16x8 a0 = ldfrag(a0p + off);
        const f16x8 a1 = ldfrag(a1p + off);
        const f16x8 b0 = ldfrag(b0p + off);
        const f16x8 b1 = ldfrag(b0p + 16L * ldbp + off);
        const f16x8 b2 = ldfrag(b0p + 32L * ldbp + off);
        const f16x8 b3 = ldfrag(b0p + 48L * ldbp + off);
        acc[0][0] = __builtin_amdgcn_mfma_f32_16x16x32_f16(a0, b0, acc[0][0], 0, 0, 0);
        acc[0][1] = __builtin_amdgcn_mfma_f32_16x16x32_f16(a0, b1, acc[0][1], 0, 0, 0);
        acc[0][2] = __builtin_amdgcn_mfma_f32_16x16x32_f16(a0, b2, acc[0][2], 0, 0, 0);
        acc[0][3] = __builtin_amdgcn_mfma_f32_16x16x32_f16(a0, b3, acc[0][3], 0, 0, 0);
        acc[1][0] = __builtin_amdgcn_mfma_f32_16x16x32_f16(a1, b0, acc[1][0], 0, 0, 0);
        acc[1][1] = __builtin_amdgcn_mfma_f32_16x16x32_f16(a1, b1, acc[1][1], 0, 0, 0);
        acc[1][2] = __builtin_amdgcn_mfma_f32_16x16x32_f16(a1, b2, acc[1][2], 0, 0, 0);
        acc[1][3] = __builtin_amdgcn_mfma_f32_16x16x32_f16(a1, b3, acc[1][3], 0, 0, 0);
    }

    #pragma unroll
    for (int mi = 0; mi < 2; ++mi) {
        #pragma unroll
        for (int bj = 0; bj < 4; ++bj) {
            const int gcol = n0 + bj * 16 + ln;
            #pragma unroll
            for (int r = 0; r < 4; ++r) {
                const int gm = m0 + mi * 16 + lh * 4 + r;
                float v = acc[mi][bj][r];
                if (gcol < N) v += (gcol < bsplit) ? bias1[gcol] : bias2[gcol - bsplit];
                if (RELU) v = fmaxf(v, 0.f);
                const float pr = PACKOUT ? __shfl_xor(v, 1) : 0.f;
                if (gcol < N) {
                    C[(long)gm * ldc + gcol] = v;
                    if (PACKOUT && !(ln & 1))
                        CPK[(long)gm * ldcp + (gcol >> 1)] = packh2(v, pr);
                }
            }
        }
    }
}

// ---------------- DAG scan v17: 24 uint4 resident weights + 14 uint4 streamed, NO scratch array ----------------
__global__ __launch_bounds__(512, 2)
void scan17(float* __restrict__ out,
            const float* __restrict__ GG,
            const unsigned int* __restrict__ PK2TL,  // row-major [1800][152]
            const float* __restrict__ cbhh,
            const float* __restrict__ pbih,
            const int* __restrict__ adj,
            const float* __restrict__ wk,
            unsigned long long* __restrict__ TBL,
            unsigned int* __restrict__ APKN,
            int l)
{
    extern __shared__ unsigned int histp[];   // [128][152] f16-pairs
    __shared__ float wsm2[NB];
    __shared__ float betas[NB];
    __shared__ float Mlds[DH];
    __shared__ __align__(16) unsigned int M2[152];
    __shared__ float gmv[456];
    __shared__ float mx2s, S_pres;

    const int tid = threadIdx.x;
    const int lane = tid & 63;
    const int wid = tid >> 6;
    const int b = blockIdx.x & 63;
    const int k = blockIdx.x >> 6;
    const int swk = (k == 3) ? 72 : 76;

    float* outb = out + (long)b * NB * OUTD;
    const float* xcol = outb + l * DH;
    float* ycol = outb + (l + 1) * DH;
    const float* ggb = GG + (long)b * NB * G6;
    const int* adjb = adj + b * NB * NB;
    unsigned long long* mb = TBL + (long)b * NB * MROW;
    unsigned int* mb32 = (unsigned int*)mb;

    if (tid < 152) M2[tid] = 0u;

    const int D = 76 * k + ((tid < swk) ? tid : 0);
    const float cb0 = cbhh[D], cb1 = cbhh[DH + D], cb2 = cbhh[2 * DH + D];
    const float pb0 = pbih[D], pb1 = pbih[DH + D], pb2 = pbih[2 * DH + D];
    const float wkD = wk[D];

    const int ROWS = 6 * swk;
    int R;
    {
        const int t = (tid < ROWS) ? tid : 0;
        const int d = t % swk;
        const int r = t / swk;
        R = (r / 3) * G3 + (r % 3) * DH + 76 * k + d;
    }
    const unsigned int* wrow = PK2TL + (long)R * WROW;
    // resident weights: kp pairs 0..95 in 24 uint4 (96 VGPRs), whole-kernel live range
    uint4 wr[24];
    #pragma unroll
    for (int q = 0; q < 24; ++q) wr[q] = *(const uint4*)(wrow + 4 * q);

    __syncthreads();

    const bool isv = (tid >= 256) && (tid < 406);
    const int vt = tid - 256;

    for (int i = 0; i < NB; ++i) {
        // ---- top-of-step prefetches ----
        float gi0 = 0, gi1 = 0, gi2 = 0, gp0 = 0, gp1 = 0, gp2 = 0, xi = 0;
        if (tid < swk) {
            const float* gic = ggb + (long)i * G6;
            gi0 = gic[D]; gi1 = gic[DH + D]; gi2 = gic[2 * DH + D];
            gp0 = gic[G3 + D]; gp1 = gic[G3 + DH + D]; gp2 = gic[G3 + 2 * DH + D];
            xi = xcol[(long)i * OUTD + D];
        }
        int a0p = 0, a1p = 0;
        if (wid == 2 && i + 1 < NB) {
            a0p = adjb[(i + 1) * NB + lane];
            a1p = adjb[(i + 1) * NB + 64 + lane];
        }

        if (i > 0) {
            float V0 = 0.f, V1 = 0.f;
            if (wid == 0) {
                const unsigned long long* trow = mb + (long)(i - 1) * MROW;
                const unsigned int tag = (unsigned int)i;
                const bool act = (lane < 8);
                unsigned long long tv = 0;
                while (true) {
                    if (act && (unsigned int)tv != tag)
                        tv = __hip_atomic_load(&trow[152 + lane],
                                               __ATOMIC_RELAXED, __HIP_MEMORY_SCOPE_AGENT);
                    if (__all(!act || (unsigned int)tv == tag)) break;
                }
                unsigned long long d0 = 0, d1 = 0;
                if (lane < 38) {
                    d0 = __hip_atomic_load(&trow[2 * lane],
                                           __ATOMIC_RELAXED, __HIP_MEMORY_SCOPE_AGENT);
                    d1 = __hip_atomic_load(&trow[2 * lane + 1],
                                           __ATOMIC_RELAXED, __HIP_MEMORY_SCOPE_AGENT);
                }
                float bp = 0.f;
                if (act) {
                    const unsigned int hb = (unsigned int)(tv >> 32);
                    __builtin_memcpy(&bp, &hb, 4);
                }
                bp += __shfl_xor(bp, 1);
                bp += __shfl_xor(bp, 2);
                bp += __shfl_xor(bp, 4);
                if (lane == 0) betas[i - 1] = __shfl(bp, 0);

                if (lane < 38) {
                    uint4 q;
                    q.x = (unsigned int)d0; q.y = (unsigned int)(d0 >> 32);
                    q.z = (unsigned int)d1; q.w = (unsigned int)(d1 >> 32);
                    *(uint4*)&histp[(i - 1) * 152 + 4 * lane] = q;
                }
            } else if (isv) {
                #pragma unroll 4
                for (int j = 0; j + 1 < i; ++j) {
                    const float wj = wsm2[j];
                    const unsigned int u = histp[j * 152 + vt];
                    __half2 h; __builtin_memcpy(&h, &u, 4);
                    V0 = fmaf(wj, __half2float(h.x), V0);
                    V1 = fmaf(wj, __half2float(h.y), V1);
                }
            }
            __syncthreads();   // B1

            if (isv) {
                const float beta_new = betas[i - 1];
                const float mxl = mx2s;
                float S = S_pres, e;
                if (beta_new > mxl) {
                    const float sc = __expf(mxl - beta_new);
                    V0 *= sc; V1 *= sc; S *= sc; e = 1.f;
                } else {
                    e = __expf(beta_new - mxl);
                }
                const unsigned int u = histp[(i - 1) * 152 + vt];
                __half2 h; __builtin_memcpy(&h, &u, 4);
                S += e;
                V0 = fmaf(e, __half2float(h.x), V0);
                V1 = fmaf(e, __half2float(h.y), V1);
                const float inv = 1.f / S;
                const float m0 = V0 * inv, m1 = V1 * inv;
                Mlds[2 * vt] = m0;
                Mlds[2 * vt + 1] = m1;
                M2[vt] = packh2(m0, m1);
            }
        } else {
            if (tid < DH) Mlds[tid] = 0.f;
        }
        __syncthreads();   // B4

        // ---- matvec: kp 0..95 from resident registers, kp 96..151 streamed from global row ----
        if (tid < ROWS) {
            float a0 = 0.f, a1 = 0.f;
            #pragma unroll
            for (int q = 0; q < 14; ++q) {
                const uint4 w4 = *(const uint4*)(wrow + 96 + 4 * q);
                const uint4 m4 = *(const uint4*)&M2[96 + 4 * q];
                a0 = dot2f(m4.x, w4.x, a0);
                a1 = dot2f(m4.y, w4.y, a1);
                a0 = dot2f(m4.z, w4.z, a0);
                a1 = dot2f(m4.w, w4.w, a1);
            }
            #pragma unroll
            for (int q = 0; q < 24; ++q) {
                const uint4 m4 = *(const uint4*)&M2[4 * q];
                a0 = dot2f(m4.x, wr[q].x, a0);
                a1 = dot2f(m4.y, wr[q].y, a1);
                a0 = dot2f(m4.z, wr[q].z, a0);
                a1 = dot2f(m4.w, wr[q].w, a1);
            }
            gmv[tid] = a0 + a1;
        }
        __syncthreads();   // B5

        // ---- gates + per-wave early release (waves 0-1) || prep next softmax (wave 2) ----
        if (wid < 2) {
            float rowv = 0.f;
            if (tid < swk) {
                const float Mi = Mlds[D];
                const float hc0 = gmv[0 * swk + tid] + cb0;
                const float hc1 = gmv[1 * swk + tid] + cb1;
                const float hc2 = gmv[2 * swk + tid] + cb2;
                const float rc = sigmoidf_(gi0 + hc0);
                const float zc = sigmoidf_(gi1 + hc1);
                const float nc = tanh_fast(gi2 + rc * hc2);
                const float Cc = (1.f - zc) * nc + zc * Mi;
                const float ip0 = gmv[3 * swk + tid] + pb0;
                const float ip1 = gmv[4 * swk + tid] + pb1;
                const float ip2 = gmv[5 * swk + tid] + pb2;
                const float rp = sigmoidf_(ip0 + gp0);
                const float zp = sigmoidf_(ip1 + gp1);
                const float np = tanh_fast(ip2 + rp * gp2);
                const float Pp = (1.f - zp) * np + zp * xi;
                rowv = Cc + Pp;
            }
            const float pr = __shfl_xor(rowv, 1);
            const unsigned int pairu32 = packh2(rowv, pr);
            if (tid < swk && !(tid & 1)) {
                __hip_atomic_store(&mb32[(long)i * (MROW * 2) + 38 * k + (tid >> 1)], pairu32,
                                   __ATOMIC_RELAXED, __HIP_MEMORY_SCOPE_AGENT);
                if (l == 0)
                    APKN[((long)b * NB + i) * 160 + 38 * k + (tid >> 1)] = pairu32;
            }
            float bv = (tid < swk) ? rowv * wkD : 0.f;
            #pragma unroll
            for (int off = 32; off; off >>= 1) bv += __shfl_xor(bv, off);
            asm volatile("s_waitcnt vmcnt(0)" ::: "memory");
            if (lane == 0) {
                unsigned int bbits;
                __builtin_memcpy(&bbits, &bv, 4);
                const unsigned long long pkt =
                    ((unsigned long long)bbits << 32) | (unsigned int)(i + 1);
                __hip_atomic_store(&mb[(long)i * MROW + 152 + 2 * k + wid], pkt,
                                   __ATOMIC_RELAXED, __HIP_MEMORY_SCOPE_AGENT);
            }
            if (tid < swk) ycol[(long)i * OUTD + D] = rowv;
        } else if (wid == 2 && i + 1 < NB) {
            const int j1 = lane + 64;
            const bool v0 = (lane < i) && (a0p != 0);
            const bool v1 = (j1 < i) && (a1p != 0);
            const float aa0 = v0 ? betas[lane] : -3.0e38f;
            const float aa1 = v1 ? betas[j1]   : -3.0e38f;
            float mx = fmaxf(aa0, aa1);
            #pragma unroll
            for (int off = 32; off; off >>= 1) mx = fmaxf(mx, __shfl_xor(mx, off));
            const float e0 = v0 ? __expf(aa0 - mx) : 0.f;
            const float e1 = v1 ? __expf(aa1 - mx) : 0.f;
            float s = e0 + e1;
            #pragma unroll
            for (int off = 32; off; off >>= 1) s += __shfl_xor(s, off);
            wsm2[lane] = e0;
            wsm2[j1]   = e1;
            if (lane == 0) { mx2s = mx; S_pres = s; }
        }
        __syncthreads();   // B6
    }
}

extern "C" void kernel_launch(void* const* d_in, const int* in_sizes, int n_in,
                              void* d_out, int out_size, void* d_ws, size_t ws_size,
                              hipStream_t stream) {
    (void)in_sizes; (void)n_in; (void)out_size; (void)ws_size;
    const float* features = (const float*)d_in[0];
    const float* fc1_w    = (const float*)d_in[1];
    const float* fc1_b    = (const float*)d_in[2];
    const float* gat_w    = (const float*)d_in[3];
    const float* gc_wih   = (const float*)d_in[5];
    const float* gc_whh   = (const float*)d_in[6];
    const float* gc_bih   = (const float*)d_in[7];
    const float* gc_bhh   = (const float*)d_in[8];
    const float* gp_wih   = (const float*)d_in[9];
    const float* gp_whh   = (const float*)d_in[10];
    const float* gp_bih   = (const float*)d_in[11];
    const float* gp_bhh   = (const float*)d_in[12];
    const int*   adj      = (const int*)d_in[13];
    float* out = (float*)d_out;

    unsigned long long* TB = (unsigned long long*)d_ws;             // 2*64*128*160 u64
    float* GG = (float*)(TB + 2L * B_ * NB * MROW);                 // 8192*1800 f32
    unsigned int* PK2T = (unsigned int*)(GG + 8192L * G6);           // 2*1800*152
    unsigned int* APK2 = PK2T + 2 * 1800 * WROW;                     // 8192*160
    unsigned int* BPKF = APK2 + 8192L * 160;                         // 320*512
    unsigned int* BPKL = BPKF + 320L * 512;                          // 2*1856*160
    unsigned int* APK1 = (unsigned int*)GG;                          // alias (dead before GG written)

    hipFuncSetAttribute(reinterpret_cast<const void*>(scan17),
                        hipFuncAttributeMaxDynamicSharedMemorySize, 80000);
    hipMemsetAsync(TB, 0, 2L * B_ * NB * MROW * sizeof(unsigned long long), stream);

    pack_all<<<dim3((NTOT + 255) / 256), 256, 0, stream>>>(
        gc_whh, gp_wih, features, fc1_w, gc_wih, gp_whh,
        PK2T, APK1, BPKF, BPKL, out, APK2);

    // H0 = relu(features @ fc1_w + b) -> out cols [0,300) f32 + APK2 packed f16 (MFMA)
    gemm_mf<1, 1><<<dim3(5, 64), 256, 0, stream>>>(
        APK1, 512, BPKF, 512, fc1_b, fc1_b, DH, out, OUTD, APK2, 160, DH, 32);

    for (int l = 0; l < 2; ++l) {
        gemm_mf<0, 0><<<dim3(29, 64), 256, 0, stream>>>(
            APK2, 160, BPKL + (long)l * BROWS * 160, 160,
            gc_bih + l * G3, gp_bhh + l * G3, G3,
            GG, G6, (unsigned int*)nullptr, 0, G6, 10);
        scan17<<<dim3(SLICES * B_), 512, 77824, stream>>>(
            out, GG, PK2T + (long)l * 1800 * WROW,
            gc_bhh + l * G3, gp_bih + l * G3, adj,
            gat_w + l * 2 * DH + DH,
            TB + (long)l * B_ * NB * MROW,
            APK2, l);
    }
}

// Round 18
// 1069.505 us; speedup vs baseline: 2.3522x; 2.3522x over previous
//
#include <hip/hip_runtime.h>
#include <hip/hip_fp16.h>

#define B_   64
#define NB   128
#define E_   1024
#define DH   300
#define G3   900
#define G6   1800
#define OUTD 1924
#define SLICES 4
#define PK_STRIDE 1800
#define MROW 160   // u64/row: u32 data words [0..149], tag u64s [152..159]
#define BROWS 1856 // padded B rows for fused layer GEMM

typedef _Float16 h2raw __attribute__((ext_vector_type(2)));
typedef _Float16 f16x8 __attribute__((ext_vector_type(8)));
typedef float f32x4 __attribute__((ext_vector_type(4)));

__device__ __forceinline__ float dot2f(unsigned int m2, unsigned int w, float acc) {
    h2raw a, b;
    __builtin_memcpy(&a, &m2, 4);
    __builtin_memcpy(&b, &w, 4);
    return __builtin_amdgcn_fdot2(a, b, acc, false);
}

__device__ __forceinline__ unsigned int packh2(float x, float y) {
    __half2 h;
    h.x = __float2half_rn(x);
    h.y = __float2half_rn(y);
    unsigned int u;
    __builtin_memcpy(&u, &h, 4);
    return u;
}

__device__ __forceinline__ float sigmoidf_(float x) { return 1.f / (1.f + __expf(-x)); }
__device__ __forceinline__ float tanh_fast(float x) { return 1.f - 2.f / (__expf(2.f * x) + 1.f); }

// ================= merged pack kernel =================
#define NA (2 * 150 * PK_STRIDE)
#define NB_SEG (8192 * 512)
#define NC (320 * 512)
#define ND (2 * BROWS * 160)
#define NE (2 * 1800 * 76)
#define NF (B_ * NB * 256)
#define NG (8192 * 10)
#define NTOT (NA + NB_SEG + NC + ND + NE + NF + NG)

__global__ __launch_bounds__(256)
void pack_all(const float* __restrict__ gc_whh, const float* __restrict__ gp_wih,
              const float* __restrict__ features, const float* __restrict__ fc1_w,
              const float* __restrict__ gc_wih, const float* __restrict__ gp_whh,
              unsigned int* __restrict__ PK2, unsigned int* __restrict__ APK1,
              unsigned int* __restrict__ BPKF, unsigned int* __restrict__ BPKL,
              unsigned int* __restrict__ PK2T, float* __restrict__ out,
              unsigned int* __restrict__ APK2)
{
    long id = (long)blockIdx.x * 256 + threadIdx.x;
    if (id >= NTOT) return;
    if (id < NA) {
        const int l   = (int)(id / (150 * PK_STRIDE));
        const int rem = (int)(id % (150 * PK_STRIDE));
        const int kp  = rem / PK_STRIDE;
        const int R   = rem % PK_STRIDE;
        const int mat = R / G3;
        const int o   = R % G3;
        const float* W = (mat ? gp_wih : gc_whh) + (long)l * G3 * DH;
        const float2 v = *(const float2*)(W + (long)o * DH + 2 * kp);
        PK2[id] = packh2(v.x, v.y);
        return;
    }
    id -= NA;
    if (id < NB_SEG) {
        const long r = id >> 9;
        const int kp = (int)(id & 511);
        const float2 v = *(const float2*)(features + r * E_ + 2 * kp);
        APK1[id] = packh2(v.x, v.y);
        return;
    }
    id -= NB_SEG;
    if (id < NC) {
        const int n = (int)(id >> 9);
        const int kp = (int)(id & 511);
        unsigned int u = 0u;
        if (n < DH) u = packh2(fc1_w[(2 * kp) * DH + n], fc1_w[(2 * kp + 1) * DH + n]);
        BPKF[id] = u;
        return;
    }
    id -= NC;
    if (id < ND) {
        const int l   = (int)(id / (BROWS * 160));
        const int rem = (int)(id % (BROWS * 160));
        const int n   = rem / 160;
        const int kp  = rem % 160;
        unsigned int u = 0u;
        if (n < G6 && kp < 150) {
            const float* W = (n < G3 ? gc_wih : gp_whh) + (long)l * G3 * DH;
            const int o = (n < G3) ? n : n - G3;
            const float2 v = *(const float2*)(W + (long)o * DH + 2 * kp);
            u = packh2(v.x, v.y);
        }
        BPKL[id] = u;
        return;
    }
    id -= ND;
    if (id < NE) {
        const int l   = (int)(id / (1800 * 76));
        const int rem = (int)(id % (1800 * 76));
        const int R   = rem / 76;
        const int kp  = rem % 76;
        const int mat = R / G3;
        const int o   = R % G3;
        const float* W = (mat ? gp_wih : gc_whh) + (long)l * G3 * DH;
        const float2 v = *(const float2*)(W + (long)o * DH + 2 * kp);
        PK2T[id] = packh2(v.x, v.y);
        return;
    }
    id -= NE;
    if (id < NF) {
        const long r = id >> 8;
        const int  c = (int)(id & 255);
        const float4 v = ((const float4*)(features + r * E_))[c];
        ((float4*)(out + r * OUTD + 3 * DH))[c] = v;
        return;
    }
    id -= NF;
    {
        const long r = id / 10;
        const int c = (int)(id % 10);
        APK2[r * 160 + 150 + c] = 0u;
    }
}

// ---------------- MFMA f16 GEMM ----------------
__device__ __forceinline__ f16x8 ldfrag(const unsigned int* p) {
    const uint4 u = *(const uint4*)p;
    f16x8 r;
    __builtin_memcpy(&r, &u, 16);
    return r;
}

template<int RELU, int PACKOUT>
__global__ __launch_bounds__(256)
void gemm_mf(const unsigned int* __restrict__ APK, int ldap,
             const unsigned int* __restrict__ BPK, int ldbp,
             const float* __restrict__ bias1, const float* __restrict__ bias2, int bsplit,
             float* __restrict__ C, int ldc,
             unsigned int* __restrict__ CPK, int ldcp,
             int N, int KSTEPS)
{
    const int lane = threadIdx.x & 63;
    const int wv = threadIdx.x >> 6;
    const int m0 = blockIdx.y * 128 + wv * 32;
    const int n0 = blockIdx.x * 64;
    const int ln = lane & 15;
    const int lh = lane >> 4;

    const unsigned int* a0p = APK + (long)(m0 + ln) * ldap + lh * 4;
    const unsigned int* a1p = a0p + 16L * ldap;
    const unsigned int* b0p = BPK + (long)(n0 + ln) * ldbp + lh * 4;

    f32x4 acc[2][4];
    #pragma unroll
    for (int mi = 0; mi < 2; ++mi)
        #pragma unroll
        for (int bj = 0; bj < 4; ++bj)
            acc[mi][bj] = (f32x4){0.f, 0.f, 0.f, 0.f};

    for (int ks = 0; ks < KSTEPS; ++ks) {
        const int off = ks * 16;
        const f16x8 a0 = ldfrag(a0p + off);
        const f16x8 a1 = ldfrag(a1p + off);
        const f16x8 b0 = ldfrag(b0p + off);
        const f16x8 b1 = ldfrag(b0p + 16L * ldbp + off);
        const f16x8 b2 = ldfrag(b0p + 32L * ldbp + off);
        const f16x8 b3 = ldfrag(b0p + 48L * ldbp + off);
        acc[0][0] = __builtin_amdgcn_mfma_f32_16x16x32_f16(a0, b0, acc[0][0], 0, 0, 0);
        acc[0][1] = __builtin_amdgcn_mfma_f32_16x16x32_f16(a0, b1, acc[0][1], 0, 0, 0);
        acc[0][2] = __builtin_amdgcn_mfma_f32_16x16x32_f16(a0, b2, acc[0][2], 0, 0, 0);
        acc[0][3] = __builtin_amdgcn_mfma_f32_16x16x32_f16(a0, b3, acc[0][3], 0, 0, 0);
        acc[1][0] = __builtin_amdgcn_mfma_f32_16x16x32_f16(a1, b0, acc[1][0], 0, 0, 0);
        acc[1][1] = __builtin_amdgcn_mfma_f32_16x16x32_f16(a1, b1, acc[1][1], 0, 0, 0);
        acc[1][2] = __builtin_amdgcn_mfma_f32_16x16x32_f16(a1, b2, acc[1][2], 0, 0, 0);
        acc[1][3] = __builtin_amdgcn_mfma_f32_16x16x32_f16(a1, b3, acc[1][3], 0, 0, 0);
    }

    #pragma unroll
    for (int mi = 0; mi < 2; ++mi) {
        #pragma unroll
        for (int bj = 0; bj < 4; ++bj) {
            const int gcol = n0 + bj * 16 + ln;
            #pragma unroll
            for (int r = 0; r < 4; ++r) {
                const int gm = m0 + mi * 16 + lh * 4 + r;
                float v = acc[mi][bj][r];
                if (gcol < N) v += (gcol < bsplit) ? bias1[gcol] : bias2[gcol - bsplit];
                if (RELU) v = fmaxf(v, 0.f);
                const float pr = PACKOUT ? __shfl_xor(v, 1) : 0.f;
                if (gcol < N) {
                    C[(long)gm * ldc + gcol] = v;
                    if (PACKOUT && !(ln & 1))
                        CPK[(long)gm * ldcp + (gcol >> 1)] = packh2(v, pr);
                }
            }
        }
    }
}

// ---------------- DAG scan v18: round-16 base, B6 removed, prep moved post-B1, parity-buffered ----------------
__global__ __launch_bounds__(512, 2)
void scan18(float* __restrict__ out,
            const float* __restrict__ GG,
            const unsigned int* __restrict__ PK2L,   // kp-major [150][1800]
            const unsigned int* __restrict__ PK2TL,  // row-major [1800][76] (kp 0..75)
            const float* __restrict__ cbhh,
            const float* __restrict__ pbih,
            const int* __restrict__ adj,
            const float* __restrict__ wk,
            unsigned long long* __restrict__ TBL,
            unsigned int* __restrict__ APKN,
            int l)
{
    extern __shared__ unsigned int histp[];   // [128][152] f16-pairs
    __shared__ float wsm2[2][NB];
    __shared__ float betas[NB];
    __shared__ float Mlds[DH];
    __shared__ __align__(16) unsigned int M2[152];
    __shared__ float gmv[456];
    __shared__ float mx2s[2], S_pres[2];

    const int tid = threadIdx.x;
    const int lane = tid & 63;
    const int wid = tid >> 6;
    const int b = blockIdx.x & 63;
    const int k = blockIdx.x >> 6;
    const int swk = (k == 3) ? 72 : 76;

    float* outb = out + (long)b * NB * OUTD;
    const float* xcol = outb + l * DH;
    float* ycol = outb + (l + 1) * DH;
    const float* ggb = GG + (long)b * NB * G6;
    const int* adjb = adj + b * NB * NB;
    unsigned long long* mb = TBL + (long)b * NB * MROW;
    unsigned int* mb32 = (unsigned int*)mb;

    if (tid < 152) M2[tid] = 0u;

    const int D = 76 * k + ((tid < swk) ? tid : 0);
    const float cb0 = cbhh[D], cb1 = cbhh[DH + D], cb2 = cbhh[2 * DH + D];
    const float pb0 = pbih[D], pb1 = pbih[DH + D], pb2 = pbih[2 * DH + D];
    const float wkD = wk[D];

    const int ROWS = 6 * swk;
    int R;
    {
        const int t = (tid < ROWS) ? tid : 0;
        const int d = t % swk;
        const int r = t / swk;
        R = (r / 3) * G3 + (r % 3) * DH + 76 * k + d;
    }
    uint4 wr[19];
    {
        const unsigned int* pkt = PK2TL + (long)R * 76;
        #pragma unroll
        for (int q = 0; q < 19; ++q) wr[q] = *(const uint4*)(pkt + 4 * q);
    }
    unsigned int ws[76];
    #pragma unroll
    for (int j = 0; j < 76; ++j)
        ws[j] = (j < 74) ? PK2L[(76 + j) * PK_STRIDE + R] : 0u;

    __syncthreads();

    const bool isv = (tid >= 256) && (tid < 406);
    const int vt = tid - 256;

    for (int i = 0; i < NB; ++i) {
        const int par = i & 1;          // read slot
        const int nxt = par ^ 1;        // write slot (for step i+1)

        // ---- top-of-step prefetches ----
        float gi0 = 0, gi1 = 0, gi2 = 0, gp0 = 0, gp1 = 0, gp2 = 0, xi = 0;
        if (tid < swk) {
            const float* gic = ggb + (long)i * G6;
            gi0 = gic[D]; gi1 = gic[DH + D]; gi2 = gic[2 * DH + D];
            gp0 = gic[G3 + D]; gp1 = gic[G3 + DH + D]; gp2 = gic[G3 + 2 * DH + D];
            xi = xcol[(long)i * OUTD + D];
        }
        int a0p = 0, a1p = 0;
        if (wid == 2 && i + 1 < NB) {
            a0p = adjb[(i + 1) * NB + lane];
            a1p = adjb[(i + 1) * NB + 64 + lane];
        }

        if (i > 0) {
            float V0 = 0.f, V1 = 0.f;
            if (wid == 0) {
                const unsigned long long* trow = mb + (long)(i - 1) * MROW;
                const unsigned int tag = (unsigned int)i;
                const bool act = (lane < 8);
                unsigned long long tv = 0;
                while (true) {
                    if (act && (unsigned int)tv != tag)
                        tv = __hip_atomic_load(&trow[152 + lane],
                                               __ATOMIC_RELAXED, __HIP_MEMORY_SCOPE_AGENT);
                    if (__all(!act || (unsigned int)tv == tag)) break;
                }
                unsigned long long d0 = 0, d1 = 0;
                if (lane < 38) {
                    d0 = __hip_atomic_load(&trow[2 * lane],
                                           __ATOMIC_RELAXED, __HIP_MEMORY_SCOPE_AGENT);
                    d1 = __hip_atomic_load(&trow[2 * lane + 1],
                                           __ATOMIC_RELAXED, __HIP_MEMORY_SCOPE_AGENT);
                }
                float bp = 0.f;
                if (act) {
                    const unsigned int hb = (unsigned int)(tv >> 32);
                    __builtin_memcpy(&bp, &hb, 4);
                }
                bp += __shfl_xor(bp, 1);
                bp += __shfl_xor(bp, 2);
                bp += __shfl_xor(bp, 4);
                if (lane == 0) betas[i - 1] = __shfl(bp, 0);

                if (lane < 38) {
                    uint4 q;
                    q.x = (unsigned int)d0; q.y = (unsigned int)(d0 >> 32);
                    q.z = (unsigned int)d1; q.w = (unsigned int)(d1 >> 32);
                    *(uint4*)&histp[(i - 1) * 152 + 4 * lane] = q;
                }
            } else if (isv) {
                #pragma unroll 4
                for (int j = 0; j + 1 < i; ++j) {
                    const float wj = wsm2[par][j];
                    const unsigned int u = histp[j * 152 + vt];
                    __half2 h; __builtin_memcpy(&h, &u, 4);
                    V0 = fmaf(wj, __half2float(h.x), V0);
                    V1 = fmaf(wj, __half2float(h.y), V1);
                }
            }
            __syncthreads();   // B1: betas[i-1] + hist row i-1 visible

            if (isv) {
                // ---- finalize M (reads slot par) ----
                const float beta_new = betas[i - 1];
                const float mxl = mx2s[par];
                float S = S_pres[par], e;
                if (beta_new > mxl) {
                    const float sc = __expf(mxl - beta_new);
                    V0 *= sc; V1 *= sc; S *= sc; e = 1.f;
                } else {
                    e = __expf(beta_new - mxl);
                }
                const unsigned int u = histp[(i - 1) * 152 + vt];
                __half2 h; __builtin_memcpy(&h, &u, 4);
                S += e;
                V0 = fmaf(e, __half2float(h.x), V0);
                V1 = fmaf(e, __half2float(h.y), V1);
                const float inv = 1.f / S;
                const float m0 = V0 * inv, m1 = V1 * inv;
                Mlds[2 * vt] = m0;
                Mlds[2 * vt + 1] = m1;
                M2[vt] = packh2(m0, m1);
            } else if (wid == 2 && i + 1 < NB) {
                // ---- prep for step i+1 (writes slot nxt; ordered vs readers by B4/B5) ----
                const int j1 = lane + 64;
                const bool v0 = (lane < i) && (a0p != 0);
                const bool v1 = (j1 < i) && (a1p != 0);
                const float aa0 = v0 ? betas[lane] : -3.0e38f;
                const float aa1 = v1 ? betas[j1]   : -3.0e38f;
                float mx = fmaxf(aa0, aa1);
                #pragma unroll
                for (int off = 32; off; off >>= 1) mx = fmaxf(mx, __shfl_xor(mx, off));
                const float e0 = v0 ? __expf(aa0 - mx) : 0.f;
                const float e1 = v1 ? __expf(aa1 - mx) : 0.f;
                float s = e0 + e1;
                #pragma unroll
                for (int off = 32; off; off >>= 1) s += __shfl_xor(s, off);
                wsm2[nxt][lane] = e0;
                wsm2[nxt][j1]   = e1;
                if (lane == 0) { mx2s[nxt] = mx; S_pres[nxt] = s; }
            }
        } else {
            if (tid < DH) Mlds[tid] = 0.f;
            if (wid == 2) {            // prep for step 1 (empty j-range -> zeros)
                wsm2[1][lane] = 0.f;
                wsm2[1][lane + 64] = 0.f;
                if (lane == 0) { mx2s[1] = -3.0e38f; S_pres[1] = 0.f; }
            }
        }
        __syncthreads();   // B4: M ready (and prep slot-nxt written)

        // ---- matvec: kp 0..75 resident/scratch mix (proven form) ----
        if (tid < ROWS) {
            float a0 = 0.f, a1 = 0.f;
            #pragma unroll
            for (int q = 0; q < 19; ++q) {
                const uint4 m4 = *(const uint4*)&M2[4 * q];
                a0 = dot2f(m4.x, wr[q].x, a0);
                a1 = dot2f(m4.y, wr[q].y, a1);
                a0 = dot2f(m4.z, wr[q].z, a0);
                a1 = dot2f(m4.w, wr[q].w, a1);
            }
            #pragma unroll
            for (int q = 0; q < 19; ++q) {
                const uint4 m4 = *(const uint4*)&M2[76 + 4 * q];
                const uint4 w4 = *(const uint4*)&ws[4 * q];
                a0 = dot2f(m4.x, w4.x, a0);
                a1 = dot2f(m4.y, w4.y, a1);
                a0 = dot2f(m4.z, w4.z, a0);
                a1 = dot2f(m4.w, w4.w, a1);
            }
            gmv[tid] = a0 + a1;
        }
        __syncthreads();   // B5: gmv ready

        // ---- gates + per-wave early release (waves 0-1); no end-of-step barrier ----
        if (wid < 2) {
            float rowv = 0.f;
            if (tid < swk) {
                const float Mi = Mlds[D];
                const float hc0 = gmv[0 * swk + tid] + cb0;
                const float hc1 = gmv[1 * swk + tid] + cb1;
                const float hc2 = gmv[2 * swk + tid] + cb2;
                const float rc = sigmoidf_(gi0 + hc0);
                const float zc = sigmoidf_(gi1 + hc1);
                const float nc = tanh_fast(gi2 + rc * hc2);
                const float Cc = (1.f - zc) * nc + zc * Mi;
                const float ip0 = gmv[3 * swk + tid] + pb0;
                const float ip1 = gmv[4 * swk + tid] + pb1;
                const float ip2 = gmv[5 * swk + tid] + pb2;
                const float rp = sigmoidf_(ip0 + gp0);
                const float zp = sigmoidf_(ip1 + gp1);
                const float np = tanh_fast(ip2 + rp * gp2);
                const float Pp = (1.f - zp) * np + zp * xi;
                rowv = Cc + Pp;
            }
            const float pr = __shfl_xor(rowv, 1);
            const unsigned int pairu32 = packh2(rowv, pr);
            if (tid < swk && !(tid & 1)) {
                __hip_atomic_store(&mb32[(long)i * (MROW * 2) + 38 * k + (tid >> 1)], pairu32,
                                   __ATOMIC_RELAXED, __HIP_MEMORY_SCOPE_AGENT);
                if (l == 0)
                    APKN[((long)b * NB + i) * 160 + 38 * k + (tid >> 1)] = pairu32;
            }
            float bv = (tid < swk) ? rowv * wkD : 0.f;
            #pragma unroll
            for (int off = 32; off; off >>= 1) bv += __shfl_xor(bv, off);
            asm volatile("s_waitcnt vmcnt(0)" ::: "memory");
            if (lane == 0) {
                unsigned int bbits;
                __builtin_memcpy(&bbits, &bv, 4);
                const unsigned long long pkt =
                    ((unsigned long long)bbits << 32) | (unsigned int)(i + 1);
                __hip_atomic_store(&mb[(long)i * MROW + 152 + 2 * k + wid], pkt,
                                   __ATOMIC_RELAXED, __HIP_MEMORY_SCOPE_AGENT);
            }
            if (tid < swk) ycol[(long)i * OUTD + D] = rowv;
        }
        // B6 removed: next iteration's B1/B4/B5 provide all remaining ordering
    }
}

extern "C" void kernel_launch(void* const* d_in, const int* in_sizes, int n_in,
                              void* d_out, int out_size, void* d_ws, size_t ws_size,
                              hipStream_t stream) {
    (void)in_sizes; (void)n_in; (void)out_size; (void)ws_size;
    const float* features = (const float*)d_in[0];
    const float* fc1_w    = (const float*)d_in[1];
    const float* fc1_b    = (const float*)d_in[2];
    const float* gat_w    = (const float*)d_in[3];
    const float* gc_wih   = (const float*)d_in[5];
    const float* gc_whh   = (const float*)d_in[6];
    const float* gc_bih   = (const float*)d_in[7];
    const float* gc_bhh   = (const float*)d_in[8];
    const float* gp_wih   = (const float*)d_in[9];
    const float* gp_whh   = (const float*)d_in[10];
    const float* gp_bih   = (const float*)d_in[11];
    const float* gp_bhh   = (const float*)d_in[12];
    const int*   adj      = (const int*)d_in[13];
    float* out = (float*)d_out;

    unsigned long long* TB = (unsigned long long*)d_ws;             // 2*64*128*160 u64
    float* GG = (float*)(TB + 2L * B_ * NB * MROW);                 // 8192*1800 f32
    unsigned int* PK2  = (unsigned int*)(GG + 8192L * G6);           // 2*150*1800
    unsigned int* APK2 = PK2 + 2 * 150 * PK_STRIDE;                  // 8192*160
    unsigned int* BPKF = APK2 + 8192L * 160;                         // 320*512
    unsigned int* BPKL = BPKF + 320L * 512;                          // 2*1856*160
    unsigned int* PK2T = BPKL + 2L * BROWS * 160;                    // 2*1800*76
    unsigned int* APK1 = (unsigned int*)GG;                          // alias (dead before GG written)

    hipFuncSetAttribute(reinterpret_cast<const void*>(scan18),
                        hipFuncAttributeMaxDynamicSharedMemorySize, 80000);
    hipMemsetAsync(TB, 0, 2L * B_ * NB * MROW * sizeof(unsigned long long), stream);

    pack_all<<<dim3((NTOT + 255) / 256), 256, 0, stream>>>(
        gc_whh, gp_wih, features, fc1_w, gc_wih, gp_whh,
        PK2, APK1, BPKF, BPKL, PK2T, out, APK2);

    // H0 = relu(features @ fc1_w + b) -> out cols [0,300) f32 + APK2 packed f16 (MFMA)
    gemm_mf<1, 1><<<dim3(5, 64), 256, 0, stream>>>(
        APK1, 512, BPKF, 512, fc1_b, fc1_b, DH, out, OUTD, APK2, 160, DH, 32);

    for (int l = 0; l < 2; ++l) {
        gemm_mf<0, 0><<<dim3(29, 64), 256, 0, stream>>>(
            APK2, 160, BPKL + (long)l * BROWS * 160, 160,
            gc_bih + l * G3, gp_bhh + l * G3, G3,
            GG, G6, (unsigned int*)nullptr, 0, G6, 10);
        scan18<<<dim3(SLICES * B_), 512, 77824, stream>>>(
            out, GG, PK2 + (long)l * 150 * PK_STRIDE,
            PK2T + (long)l * 1800 * 76,
            gc_bhh + l * G3, gp_bih + l * G3, adj,
            gat_w + l * 2 * DH + DH,
            TB + (long)l * B_ * NB * MROW,
            APK2, l);
    }
}